// Round 1
// baseline (5375.743 us; speedup 1.0000x reference)
//
#include <hip/hip_runtime.h>
#include <math.h>

// Elman RNN: out[b][t][j] = H_t, H_t = tanh(X_t @ W_xh + H_{t-1} @ W_hh + b)
// Phase 1: proj_gemm writes Xp = X@W_xh + b into d_out's [B,S,H] region.
// Phase 2: ONE persistent kernel runs all 1024 steps.
//
// R5 protocol rewrite (latency-bound per counters: VALUBusy 26.5%, HBM 0.9%):
//  - per-producer monotonic counters cnt[8][32] (relaxed agent atomic STORES,
//    no RMW) replace the 32-way same-address fetch_add (L3 serialization).
//  - poll is per-thread and fused with staging: each thread waits on exactly
//    the producer whose 4 qwords it stages, then loads. No tid0 poll, no
//    s_sleep, no broadcast barrier.
//  - 2 barriers/step (post-stage, post-reduce) instead of 4. Epilogue is ONE
//    wave (tid<64, 2 outputs each): it drains its own stores with a wave-local
//    s_waitcnt vmcnt(0), lane0 publishes the counter, and the other 7 waves
//    have already launched next-step polls/loads.
//  - Xp prefetched at loop top (plain loads, overlap poll/stage; drained at
//    the pre-epilogue barrier).
//  - fast tanh (exp2 identity), error ~3 ulp << absmax budget.
// All cross-block H traffic stays agent-scope RELAXED atomics (complete at
// L3, coherent across XCDs). NO __threadfence (round-3 failure: full-L2
// writeback walks). W_hh strip stays asm-pinned in registers (round-3 bug:
// compiler re-loaded W every step).

#define B_SZ 32
#define S_SZ 1024
#define H_SZ 1024
#define K_SZ 1024

// ---------------- Phase 1: input projection GEMM (fp32) ----------------
#define BM 128
#define BN 128
#define BK 8

__global__ __launch_bounds__(256) void proj_gemm(
    const float* __restrict__ A,     // X   [M,K]
    const float* __restrict__ Bm,    // W_xh[K,N]
    const float* __restrict__ bias,  // [N]
    float* __restrict__ C,           // [M,N] (d_out Xp region)
    int M, int N, int K)
{
    __shared__ float As[BK][BM];   // transposed: As[k][m]
    __shared__ float Bs[BK][BN];

    const int tid  = threadIdx.x;
    const int row0 = blockIdx.y * BM;
    const int col0 = blockIdx.x * BN;
    const int tx = tid & 15;
    const int ty = tid >> 4;
    const int mBase = ty * 8;
    const int nBase = tx * 8;

    float acc[8][8];
    #pragma unroll
    for (int i = 0; i < 8; ++i)
        #pragma unroll
        for (int j = 0; j < 8; ++j) acc[i][j] = 0.f;

    for (int k0 = 0; k0 < K; k0 += BK) {
        {
            const int r  = tid >> 1;
            const int kq = (tid & 1) * 4;
            const float4 av = *(const float4*)(&A[(size_t)(row0 + r) * K + k0 + kq]);
            As[kq + 0][r] = av.x;
            As[kq + 1][r] = av.y;
            As[kq + 2][r] = av.z;
            As[kq + 3][r] = av.w;
            const int kr = tid >> 5;
            const int cq = (tid & 31) * 4;
            *(float4*)(&Bs[kr][cq]) =
                *(const float4*)(&Bm[(size_t)(k0 + kr) * N + col0 + cq]);
        }
        __syncthreads();

        #pragma unroll
        for (int kk = 0; kk < BK; ++kk) {
            float a[8], b[8];
            *(float4*)&a[0] = *(const float4*)&As[kk][mBase];
            *(float4*)&a[4] = *(const float4*)&As[kk][mBase + 4];
            *(float4*)&b[0] = *(const float4*)&Bs[kk][nBase];
            *(float4*)&b[4] = *(const float4*)&Bs[kk][nBase + 4];
            #pragma unroll
            for (int i = 0; i < 8; ++i)
                #pragma unroll
                for (int j = 0; j < 8; ++j)
                    acc[i][j] += a[i] * b[j];
        }
        __syncthreads();
    }

    #pragma unroll
    for (int i = 0; i < 8; ++i) {
        const int r = row0 + mBase + i;
        #pragma unroll
        for (int jq = 0; jq < 8; jq += 4) {
            const int c = col0 + nBase + jq;
            const float4 bv = *(const float4*)(&bias[c]);
            float4 o;
            o.x = acc[i][jq + 0] + bv.x;
            o.y = acc[i][jq + 1] + bv.y;
            o.z = acc[i][jq + 2] + bv.z;
            o.w = acc[i][jq + 3] + bv.w;
            *(float4*)(&C[(size_t)r * N + c]) = o;
        }
    }
}

// ---------------- init: zero the sync counters in d_ws ----------------
__global__ void init_cnt(unsigned int* __restrict__ cnt, int n) {
    int i = blockIdx.x * 256 + threadIdx.x;
    if (i < n) cnt[i] = 0u;
}

// fast tanh: tanh(x) = (e^{2x}-1)/(e^{2x}+1). Clamp keeps exp finite; output
// error ~3 ulp absolute on [-1,1] — negligible vs the 3.9e-3 absmax budget.
__device__ __forceinline__ float fast_tanh(float x) {
    const float cx = fminf(fmaxf(x, -15.f), 15.f);
    const float e  = __expf(2.f * cx);
    return __fdividef(e - 1.f, e + 1.f);
}

// ---------------- Phase 2: persistent recurrence kernel ----------------
// 256 blocks x 512 threads, 1 block/CU (grid == #CUs => co-resident).
// Block (g = blockIdx&7, c = blockIdx>>3): batches [4g,4g+4), cols [32c,+32).
// MAC partition: thread (j = tid&31 -> col, seg = tid>>5 -> K [64*seg,+64)).
// Staging partition: thread (sb = tid>>7 -> batch, sr = tid&127 -> qwords
// [4sr,4sr+4)); those 4 qwords lie inside ONE producer's (sp = sr>>2)
// 32-column region, so the thread polls exactly cnt[g][sp].
// cnt[g][c] = number of steps block (g,c) has published (monotonic).
__global__ __launch_bounds__(512, 2) void rnn_persist(
    float* __restrict__ HS,        // d_out [B][S][H]; Xp in, H out (in place)
    const float* __restrict__ W,   // W_hh [K][H]
    float* __restrict__ Hlast,     // d_out + B*S*H
    unsigned int* __restrict__ cnt // [8][32] per-producer step counters
    )
{
    const int g    = blockIdx.x & 7;
    const int c    = blockIdx.x >> 3;
    const int col0 = c * 32;
    const int b0   = g * 4;
    const int tid  = threadIdx.x;
    const int j    = tid & 31;
    const int seg  = tid >> 5;          // 0..15

    __shared__ __align__(16) float Hs[4][1024];     // H_{t-1} for 4 batches
    __shared__ float red[8][4][32];                 // per-wave partials

    // Load W strip into registers (once), then pin: asm makes the values
    // opaque so the compiler cannot sink/rematerialize the loads into the
    // t-loop (round-3 bug: VGPR_Count=52 => W re-loaded every step).
    float w[64];
    {
        const float* wp = W + (size_t)(seg * 64) * H_SZ + col0 + j;
        #pragma unroll
        for (int i = 0; i < 64; ++i) w[i] = wp[(size_t)i * H_SZ];
        #pragma unroll
        for (int i = 0; i < 64; ++i) asm volatile("" : "+v"(w[i]));
    }

    unsigned int* gcnt  = cnt + g * 32;
    unsigned int* mycnt = gcnt + c;

    // staging map
    const int sb = tid >> 7;            // batch 0..3
    const int sr = tid & 127;           // 128 threads per batch, 4 qwords each
    const unsigned int* pollp = gcnt + (sr >> 2);   // producer I stage from

    // epilogue map (wave 0 only): lanes 0..63 own (be,je) and (be+2,je)
    const int je = tid & 31;
    const int be = (tid >> 5) & 1;

    for (int t = 0; t < S_SZ; ++t) {
        // ---- Xp prefetch for this step (wave 0; plain loads, first touch;
        //      issued before poll/stage so latency hides under them) ----
        float xp0 = 0.f, xp1 = 0.f;
        if (tid < 64) {
            xp0 = HS[((size_t)(b0 + be)     * S_SZ + t) * H_SZ + col0 + je];
            xp1 = HS[((size_t)(b0 + be + 2) * S_SZ + t) * H_SZ + col0 + je];
        }

        if (t > 0) {
            // ---- wait for MY producer (parallel per-thread poll) ----
            unsigned int v;
            do {
                v = __hip_atomic_load(pollp, __ATOMIC_RELAXED,
                                      __HIP_MEMORY_SCOPE_AGENT);
            } while (v < (unsigned int)t);

            // ---- stage my 4 qwords of H_{t-1} (agent atomics: L3-fresh) ----
            const unsigned long long* src = (const unsigned long long*)
                (&HS[((size_t)(b0 + sb) * S_SZ + (t - 1)) * H_SZ]);
            const unsigned long long v0 = __hip_atomic_load(
                src + 4 * sr + 0, __ATOMIC_RELAXED, __HIP_MEMORY_SCOPE_AGENT);
            const unsigned long long v1 = __hip_atomic_load(
                src + 4 * sr + 1, __ATOMIC_RELAXED, __HIP_MEMORY_SCOPE_AGENT);
            const unsigned long long v2 = __hip_atomic_load(
                src + 4 * sr + 2, __ATOMIC_RELAXED, __HIP_MEMORY_SCOPE_AGENT);
            const unsigned long long v3 = __hip_atomic_load(
                src + 4 * sr + 3, __ATOMIC_RELAXED, __HIP_MEMORY_SCOPE_AGENT);
            unsigned long long* dst = (unsigned long long*)(&Hs[sb][8 * sr]);
            dst[0] = v0; dst[1] = v1; dst[2] = v2; dst[3] = v3;
            __syncthreads();   // barrier A: Hs staged (lgkm drained by sync)

            // ---- MAC: acc[b] = sum_{k in seg range} H[b][k] * W[k][j] ----
            float acc[4];
            #pragma unroll
            for (int b = 0; b < 4; ++b) {
                const float4* hb = (const float4*)(&Hs[b][seg * 64]);
                float a = 0.f;
                #pragma unroll
                for (int q = 0; q < 16; ++q) {
                    const float4 h = hb[q];   // broadcast across 32 j-lanes
                    a += h.x * w[4 * q + 0];
                    a += h.y * w[4 * q + 1];
                    a += h.z * w[4 * q + 2];
                    a += h.w * w[4 * q + 3];
                }
                acc[b] = a;
            }
            // combine the two k-halves within the wave (seg ^ 1)
            #pragma unroll
            for (int b = 0; b < 4; ++b) acc[b] += __shfl_xor(acc[b], 32);
            const int wv = tid >> 6;
            if ((tid & 63) < 32) {
                #pragma unroll
                for (int b = 0; b < 4; ++b) red[wv][b][j] = acc[b];
            }
        }
        __syncthreads();       // barrier B: red ready (t=0: pure alignment)

        // ---- epilogue: ONE wave owns all 4b x 32j outputs (2 each) ----
        if (tid < 64) {
            float s0 = 0.f, s1 = 0.f;
            if (t > 0) {
                #pragma unroll
                for (int wv2 = 0; wv2 < 8; ++wv2) {
                    s0 += red[wv2][be][je];
                    s1 += red[wv2][be + 2][je];
                }
            }
            const float h0 = fast_tanh(xp0 + s0);
            const float h1 = fast_tanh(xp1 + s1);
            const size_t i0 = ((size_t)(b0 + be)     * S_SZ + t) * H_SZ + col0 + je;
            const size_t i1 = ((size_t)(b0 + be + 2) * S_SZ + t) * H_SZ + col0 + je;
            // publish H_t at the agent coherent point (cache-bypassing)
            __hip_atomic_store((float*)&HS[i0], h0, __ATOMIC_RELAXED,
                               __HIP_MEMORY_SCOPE_AGENT);
            __hip_atomic_store((float*)&HS[i1], h1, __ATOMIC_RELAXED,
                               __HIP_MEMORY_SCOPE_AGENT);
            if (t == S_SZ - 1) {
                Hlast[(size_t)(b0 + be)     * H_SZ + col0 + je] = h0;
                Hlast[(size_t)(b0 + be + 2) * H_SZ + col0 + je] = h1;
            }
            // drain THIS wave's stores (all 128 outputs come from wave 0),
            // then publish the step counter. No block barrier needed: the
            // other 7 waves are already polling/staging step t+1.
            asm volatile("s_waitcnt vmcnt(0)" ::: "memory");
            if (tid == 0) {
                __hip_atomic_store(mycnt, (unsigned int)(t + 1),
                                   __ATOMIC_RELAXED, __HIP_MEMORY_SCOPE_AGENT);
            }
        }
        // No end-of-step barrier: Hs rewrite (next staging) is safe because
        // every wave's MAC reads completed before barrier B; red rewrite is
        // safe because it happens after the NEXT barrier A, which wave 0 only
        // reaches after finishing this epilogue.
    }
}

extern "C" void kernel_launch(void* const* d_in, const int* in_sizes, int n_in,
                              void* d_out, int out_size, void* d_ws, size_t ws_size,
                              hipStream_t stream) {
    const float* X    = (const float*)d_in[0];  // [B,S,K]
    const float* W_xh = (const float*)d_in[1];  // [K,H]
    const float* W_hh = (const float*)d_in[2];  // [H,H]
    const float* b_h  = (const float*)d_in[3];  // [H]
    float* out = (float*)d_out;
    float* Hlast = out + (size_t)B_SZ * S_SZ * H_SZ;
    unsigned int* cnt = (unsigned int*)d_ws;    // [8][32] counters (1 KB)

    // zero sync counters (d_ws is re-poisoned before every launch)
    init_cnt<<<1, 256, 0, stream>>>(cnt, 8 * 32);

    // Phase 1: Xp = X @ W_xh + b into d_out's [B,S,H] region.
    dim3 gridA(H_SZ / BN, (B_SZ * S_SZ) / BM);
    proj_gemm<<<gridA, 256, 0, stream>>>(X, W_xh, b_h, out,
                                         B_SZ * S_SZ, H_SZ, K_SZ);

    // Phase 2: all 1024 recurrence steps in one persistent kernel.
    rnn_persist<<<256, 512, 0, stream>>>(out, W_hh, Hlast, cnt);
}